// Round 6
// baseline (1325.303 us; speedup 1.0000x reference)
//
#include <hip/hip_runtime.h>
#include <hip/hip_fp16.h>
#include <math.h>

#define N_NODES 200000
#define N_EDGES 6400000
#define F_INF   512
#define HID     16
#define NCLS    7

#define NPB      256                               // nodes per bucket
#define NBUCKET  ((N_NODES + NPB - 1) / NPB)       // 782
#define CHUNK    16384
#define NBLKE    ((N_EDGES + CHUNK - 1) / CHUNK)   // 391
#define STAGE_CAP 9216                             // mean 8192, sigma~90 -> 11 sigma headroom

#define TM   64      // rows per block in gemm1
#define KC   128     // K-chunk
#define XPAD 132     // LDS row stride (floats): 132%32=4 -> 2-way max on compute reads

// ======================= pack W1|root1 -> interleaved Wc[512][48] =======================
// Wc[k][3c+0]=W1[0][k][c], Wc[k][3c+1]=W1[1][k][c], Wc[k][3c+2]=root1[k][c]
__global__ __launch_bounds__(256) void packW_kernel(
    const float* __restrict__ W1, const float* __restrict__ root1,
    float* __restrict__ Wc) {
    int t = blockIdx.x * 256 + threadIdx.x;     // 8192 = 512*16
    if (t >= F_INF * HID) return;
    int k = t >> 4, c = t & 15;
    Wc[k * 48 + 3 * c + 0] = W1[k * HID + c];
    Wc[k * 48 + 3 * c + 1] = W1[F_INF * HID + k * HID + c];
    Wc[k * 48 + 3 * c + 2] = root1[k * HID + c];
}

// ======================= layer 1 GEMM (tiled, coalesced) =======================
// hbufH[n*16+c] = half2(h0_c, h1_c) ; rbufH[n*16+c] = half(root contribution)
__global__ __launch_bounds__(256) void gemm1_kernel(
    const float* __restrict__ x, const float* __restrict__ Wc,
    __half2* __restrict__ hbufH, __half* __restrict__ rbufH) {
    __shared__ float xs[TM][XPAD];               // 33.8 KB
    int tid  = threadIdx.x;
    int lane = tid & 63, w = tid >> 6;
    int rowBlock = blockIdx.x * TM;
    int r = tid >> 2;                            // 0..63: my row
    int q = tid & 3;                             // channel quad -> channels q*4..q*4+3
    int jbase = q * 12;
    float acc[12];
    #pragma unroll
    for (int j = 0; j < 12; ++j) acc[j] = 0.f;

    int colg = lane & 31;                        // float4 slot in chunk
    for (int ch = 0; ch < F_INF / KC; ++ch) {
        __syncthreads();                         // xs reads from prev iter done
        #pragma unroll
        for (int i = 0; i < 8; ++i) {
            int rr = i * 8 + w * 2 + (lane >> 5);
            float4 v = *(const float4*)(x + (size_t)(rowBlock + rr) * F_INF
                                          + ch * KC + colg * 4);
            *(float4*)(&xs[rr][colg * 4]) = v;
        }
        __syncthreads();
        const float* __restrict__ WcC = Wc + (size_t)ch * KC * 48;
        for (int k4 = 0; k4 < KC / 4; ++k4) {
            float4 xv = *(const float4*)(&xs[r][k4 * 4]);
            #pragma unroll
            for (int kk = 0; kk < 4; ++kk) {
                float xsc = (kk == 0) ? xv.x : (kk == 1) ? xv.y : (kk == 2) ? xv.z : xv.w;
                const float* wk = WcC + (k4 * 4 + kk) * 48 + jbase;
                float4 w0 = *(const float4*)(wk);
                float4 w1 = *(const float4*)(wk + 4);
                float4 w2 = *(const float4*)(wk + 8);
                acc[0]  = fmaf(xsc, w0.x, acc[0]);
                acc[1]  = fmaf(xsc, w0.y, acc[1]);
                acc[2]  = fmaf(xsc, w0.z, acc[2]);
                acc[3]  = fmaf(xsc, w0.w, acc[3]);
                acc[4]  = fmaf(xsc, w1.x, acc[4]);
                acc[5]  = fmaf(xsc, w1.y, acc[5]);
                acc[6]  = fmaf(xsc, w1.z, acc[6]);
                acc[7]  = fmaf(xsc, w1.w, acc[7]);
                acc[8]  = fmaf(xsc, w2.x, acc[8]);
                acc[9]  = fmaf(xsc, w2.y, acc[9]);
                acc[10] = fmaf(xsc, w2.z, acc[10]);
                acc[11] = fmaf(xsc, w2.w, acc[11]);
            }
        }
    }
    int n = rowBlock + r;
    int cb = q * 4;
    __half2* hb = hbufH + (size_t)n * HID + cb;
    __half*  rb = rbufH + (size_t)n * HID + cb;
    #pragma unroll
    for (int c = 0; c < 4; ++c) {
        hb[c] = __floats2half2_rn(acc[c * 3 + 0], acc[c * 3 + 1]);
        rb[c] = __float2half(acc[c * 3 + 2]);
    }
}

// ======================= P1: per-block bucket histogram =======================
__global__ __launch_bounds__(256) void p1_bincount(const int* __restrict__ dst,
                                                   int* __restrict__ blockOff) {
    __shared__ int hist[NBUCKET];
    int tid = threadIdx.x;
    for (int i = tid; i < NBUCKET; i += 256) hist[i] = 0;
    __syncthreads();
    size_t base = (size_t)blockIdx.x * CHUNK;
    for (int i = 0; i < CHUNK / 256; ++i) {
        size_t e = base + (size_t)i * 256 + tid;
        if (e < N_EDGES) atomicAdd(&hist[dst[e] >> 8], 1);
    }
    __syncthreads();
    for (int i = tid; i < NBUCKET; i += 256)
        blockOff[(size_t)i * NBLKE + blockIdx.x] = hist[i];
}

// ======================= P2a: per-bucket scan over blocks =======================
__global__ __launch_bounds__(256) void p2a_kernel(int* __restrict__ blockOff,
                                                  int* __restrict__ bucketTotal) {
    __shared__ int wsum[4];
    int b = blockIdx.x, tid = threadIdx.x;
    size_t rowb = (size_t)b * NBLKE;
    int i0 = tid * 2, i1 = i0 + 1;
    int v0 = (i0 < NBLKE) ? blockOff[rowb + i0] : 0;
    int v1 = (i1 < NBLKE) ? blockOff[rowb + i1] : 0;
    int s = v0 + v1;
    int lane = tid & 63, wid = tid >> 6;
    int incl = s;
    #pragma unroll
    for (int o = 1; o < 64; o <<= 1) {
        int t = __shfl_up(incl, o, 64);
        if (lane >= o) incl += t;
    }
    if (lane == 63) wsum[wid] = incl;
    __syncthreads();
    int woff = 0;
    for (int w = 0; w < wid; ++w) woff += wsum[w];
    int excl = woff + incl - s;
    if (i0 < NBLKE) blockOff[rowb + i0] = excl;
    if (i1 < NBLKE) blockOff[rowb + i1] = excl + v0;
    if (tid == 255) bucketTotal[b] = woff + incl;
}

// ======================= P2b: scan bucket totals -> bucketStart =======================
__global__ __launch_bounds__(256) void p2b_kernel(const int* __restrict__ bucketTotal,
                                                  int* __restrict__ bucketStart,
                                                  int* __restrict__ rowptr) {
    __shared__ int wsum[4];
    int tid = threadIdx.x;
    int base = tid * 4;
    int v[4]; int s = 0;
    #pragma unroll
    for (int q = 0; q < 4; ++q) {
        int idx = base + q;
        v[q] = (idx < NBUCKET) ? bucketTotal[idx] : 0;
        s += v[q];
    }
    int lane = tid & 63, wid = tid >> 6;
    int incl = s;
    #pragma unroll
    for (int o = 1; o < 64; o <<= 1) {
        int t = __shfl_up(incl, o, 64);
        if (lane >= o) incl += t;
    }
    if (lane == 63) wsum[wid] = incl;
    __syncthreads();
    int woff = 0;
    for (int w = 0; w < wid; ++w) woff += wsum[w];
    int run = woff + incl - s;
    #pragma unroll
    for (int q = 0; q < 4; ++q) {
        int idx = base + q;
        if (idx < NBUCKET) bucketStart[idx] = run;
        run += v[q];
    }
    if (tid == 0) rowptr[N_NODES] = N_EDGES;
}

// ======================= P3: binned scatter of payload =======================
__global__ __launch_bounds__(256) void p3_binscatter(
    const int* __restrict__ dst, const int* __restrict__ src,
    const float* __restrict__ eattr,
    const int* __restrict__ blockOff, const int* __restrict__ bucketStart,
    unsigned int* __restrict__ metaArr, __half* __restrict__ wHarr) {
    __shared__ int cur[NBUCKET];
    int tid = threadIdx.x;
    for (int i = tid; i < NBUCKET; i += 256)
        cur[i] = bucketStart[i] + blockOff[(size_t)i * NBLKE + blockIdx.x];
    __syncthreads();
    size_t base = (size_t)blockIdx.x * CHUNK;
    for (int i = 0; i < CHUNK / 256; ++i) {
        size_t e = base + (size_t)i * 256 + tid;
        if (e < N_EDGES) {
            int d = dst[e];
            int b = d >> 8;
            int slot = atomicAdd(&cur[b], 1);
            unsigned int meta = ((unsigned int)(d & 255) << 18) | (unsigned int)src[e];
            float w = fminf(fmaxf(eattr[e], 0.f), 1.f);
            metaArr[slot] = meta;
            wHarr[slot] = __float2half(w);
        }
    }
}

// ======================= P4: per-bucket fine sort -> CSR + rowptr =======================
__global__ __launch_bounds__(256) void p4_buildcsr(
    const int* __restrict__ bucketStart, const int* __restrict__ bucketTotal,
    unsigned int* __restrict__ metaArr, __half* __restrict__ wHarr,
    int* __restrict__ rowptr) {
    __shared__ unsigned int stageM[STAGE_CAP];
    __shared__ __half stageW[STAGE_CAP];
    __shared__ int hist[NPB];
    __shared__ int wsum[4];
    int b = blockIdx.x, tid = threadIdx.x;
    int start = bucketStart[b];
    int count = bucketTotal[b];
    int nn = min(NPB, N_NODES - b * NPB);
    hist[tid] = 0;
    __syncthreads();
    for (int i = tid; i < count; i += 256) {
        unsigned int m = metaArr[start + i];
        stageM[i] = m;
        stageW[i] = wHarr[start + i];
        atomicAdd(&hist[m >> 18], 1);
    }
    __syncthreads();
    int v = hist[tid];
    int lane = tid & 63, wid = tid >> 6;
    int incl = v;
    #pragma unroll
    for (int o = 1; o < 64; o <<= 1) {
        int t = __shfl_up(incl, o, 64);
        if (lane >= o) incl += t;
    }
    if (lane == 63) wsum[wid] = incl;
    __syncthreads();
    int woff = 0;
    for (int w = 0; w < wid; ++w) woff += wsum[w];
    int excl = woff + incl - v;
    if (tid < nn) rowptr[b * NPB + tid] = start + excl;
    __syncthreads();
    hist[tid] = excl;
    __syncthreads();
    for (int i = tid; i < count; i += 256) {
        unsigned int m = stageM[i];
        int local = (int)(m >> 18);
        int pos = start + atomicAdd(&hist[local], 1);
        metaArr[pos] = m & 0x3FFFFu;
        wHarr[pos] = stageW[i];
    }
}

// ======================= agg1: gather-aggregate + ELU (16 lanes/node) =======================
__global__ __launch_bounds__(256) void agg1_kernel(
    const unsigned int* __restrict__ metaArr, const __half* __restrict__ wHarr,
    const int* __restrict__ rowptr, const __half2* __restrict__ hbufH,
    __half* __restrict__ rbufH, const float* __restrict__ bias1) {
    int t = blockIdx.x * 256 + threadIdx.x;
    int n = t >> 4;
    if (n >= N_NODES) return;
    int c = t & 15;
    int beg = rowptr[n], end = rowptr[n + 1];
    float acc = 0.f;
    for (int p = beg; p < end; ++p) {
        int s = (int)metaArr[p];
        float b1 = __half2float(wHarr[p]);
        float2 h = __half22float2(hbufH[(size_t)s * HID + c]);
        acc += fmaf(b1, h.y - h.x, h.x);
    }
    float invd = 1.0f / fmaxf((float)(end - beg), 1.0f);
    float r = __half2float(rbufH[(size_t)n * HID + c]);
    float vv = fmaf(acc, invd, r) + bias1[c];
    float hv = vv > 0.f ? vv : expm1f(vv);
    rbufH[(size_t)n * HID + c] = __float2half(hv);
}

// ======================= node1b: tiny layer-2 transforms =======================
__global__ __launch_bounds__(256) void node1b_kernel(
    const __half* __restrict__ rbufH, const float* __restrict__ W2,
    const float* __restrict__ root2,
    __half2* __restrict__ h2buf, float* __restrict__ r2buf) {
    int n = blockIdx.x * 256 + threadIdx.x;
    if (n >= N_NODES) return;
    float h[HID];
    #pragma unroll
    for (int k = 0; k < HID; ++k) h[k] = __half2float(rbufH[(size_t)n * HID + k]);
    float o0[NCLS], o1[NCLS], orr[NCLS];
    #pragma unroll
    for (int j = 0; j < NCLS; ++j) { o0[j] = 0.f; o1[j] = 0.f; orr[j] = 0.f; }
    const float* __restrict__ W2b = W2 + HID * NCLS;
    #pragma unroll
    for (int k = 0; k < HID; ++k) {
        #pragma unroll
        for (int j = 0; j < NCLS; ++j) {
            o0[j]  = fmaf(h[k], W2 [k * NCLS + j], o0[j]);
            o1[j]  = fmaf(h[k], W2b[k * NCLS + j], o1[j]);
            orr[j] = fmaf(h[k], root2[k * NCLS + j], orr[j]);
        }
    }
    __half2* hb = h2buf + (size_t)n * 8;
    float*   r2 = r2buf + (size_t)n * 8;
    #pragma unroll
    for (int j = 0; j < NCLS; ++j) {
        hb[j] = __floats2half2_rn(o0[j], o1[j]);
        r2[j] = orr[j];
    }
    hb[7] = __floats2half2_rn(0.f, 0.f);
    r2[7] = 0.f;
}

// ======================= agg2: gather-aggregate + log_softmax (8 lanes/node) ==========
__global__ __launch_bounds__(256) void agg2_kernel(
    const unsigned int* __restrict__ metaArr, const __half* __restrict__ wHarr,
    const int* __restrict__ rowptr, const __half2* __restrict__ h2buf,
    const float* __restrict__ r2buf, const float* __restrict__ bias2,
    float* __restrict__ out) {
    int t = blockIdx.x * 256 + threadIdx.x;
    int n = t >> 3;
    if (n >= N_NODES) return;
    int j = t & 7;
    int beg = rowptr[n], end = rowptr[n + 1];
    float acc = 0.f;
    for (int p = beg; p < end; ++p) {
        int s = (int)metaArr[p];
        float b1 = __half2float(wHarr[p]);
        float2 m = __half22float2(h2buf[(size_t)s * 8 + j]);
        acc += fmaf(b1, m.y - m.x, m.x);
    }
    float invd = 1.0f / fmaxf((float)(end - beg), 1.0f);
    float v = fmaf(acc, invd, r2buf[(size_t)n * 8 + j]) + ((j < NCLS) ? bias2[j] : 0.f);
    if (j == NCLS) v = -INFINITY;
    float mx = v;
    mx = fmaxf(mx, __shfl_xor(mx, 1, 8));
    mx = fmaxf(mx, __shfl_xor(mx, 2, 8));
    mx = fmaxf(mx, __shfl_xor(mx, 4, 8));
    float ex = expf(v - mx);
    float sm = ex;
    sm += __shfl_xor(sm, 1, 8);
    sm += __shfl_xor(sm, 2, 8);
    sm += __shfl_xor(sm, 4, 8);
    float lse = mx + logf(sm);
    if (j < NCLS) out[(size_t)n * NCLS + j] = v - lse;
}

extern "C" void kernel_launch(void* const* d_in, const int* in_sizes, int n_in,
                              void* d_out, int out_size, void* d_ws, size_t ws_size,
                              hipStream_t stream) {
    const float* x     = (const float*)d_in[0];
    const float* eattr = (const float*)d_in[1];
    const int*   src   = (const int*)d_in[2];
    const int*   dst   = (const int*)d_in[3];
    const float* W1    = (const float*)d_in[4];
    const float* root1 = (const float*)d_in[5];
    const float* bias1 = (const float*)d_in[6];
    const float* W2    = (const float*)d_in[7];
    const float* root2 = (const float*)d_in[8];
    const float* bias2 = (const float*)d_in[9];
    float* out = (float*)d_out;

    // ---------- workspace layout (~60 MB) ----------
    char* wp = (char*)d_ws;
    unsigned int* metaArr = (unsigned int*)wp;  wp += (size_t)N_EDGES * 4;           // 25.6 MB
    __half*       wHarr   = (__half*)wp;        wp += (size_t)N_EDGES * 2;           // 12.8 MB
    int* blockOff    = (int*)wp;                wp += (size_t)NBUCKET * NBLKE * 4;   // 1.22 MB
    int* bucketTotal = (int*)wp;                wp += 1024 * 4;
    int* bucketStart = (int*)wp;                wp += 1024 * 4;
    int* rowptr      = (int*)wp;                wp += (size_t)(N_NODES + 4) * 4;     // 0.8 MB
    float* Wc        = (float*)wp;              wp += (size_t)F_INF * 48 * 4;        // 98 KB
    __half2* hbufH   = (__half2*)wp;            wp += (size_t)N_NODES * HID * 4;     // 12.8 MB
    __half*  rbufH   = (__half*)wp;             wp += (size_t)N_NODES * HID * 2;     // 6.4 MB
    // aliases: hbufH region is dead after agg1
    __half2* h2buf = hbufH;                                          // N*8 half2
    float*   r2buf = (float*)(hbufH + (size_t)N_NODES * 8);          // N*8 f32

    const int node_blocks = (N_NODES + 255) / 256;  // 782

    hipLaunchKernelGGL(packW_kernel, dim3((F_INF * HID + 255) / 256), dim3(256), 0, stream,
                       W1, root1, Wc);
    hipLaunchKernelGGL(gemm1_kernel, dim3(N_NODES / TM), dim3(256), 0, stream,
                       x, Wc, hbufH, rbufH);
    hipLaunchKernelGGL(p1_bincount, dim3(NBLKE), dim3(256), 0, stream, dst, blockOff);
    hipLaunchKernelGGL(p2a_kernel, dim3(NBUCKET), dim3(256), 0, stream,
                       blockOff, bucketTotal);
    hipLaunchKernelGGL(p2b_kernel, dim3(1), dim3(256), 0, stream,
                       bucketTotal, bucketStart, rowptr);
    hipLaunchKernelGGL(p3_binscatter, dim3(NBLKE), dim3(256), 0, stream,
                       dst, src, eattr, blockOff, bucketStart, metaArr, wHarr);
    hipLaunchKernelGGL(p4_buildcsr, dim3(NBUCKET), dim3(256), 0, stream,
                       bucketStart, bucketTotal, metaArr, wHarr, rowptr);
    hipLaunchKernelGGL(agg1_kernel, dim3((N_NODES * 16 + 255) / 256), dim3(256), 0, stream,
                       metaArr, wHarr, rowptr, hbufH, rbufH, bias1);
    hipLaunchKernelGGL(node1b_kernel, dim3(node_blocks), dim3(256), 0, stream,
                       rbufH, W2, root2, h2buf, r2buf);
    hipLaunchKernelGGL(agg2_kernel, dim3((N_NODES * 8 + 255) / 256), dim3(256), 0, stream,
                       metaArr, wHarr, rowptr, h2buf, r2buf, bias2, out);
}

// Round 7
// 1027.784 us; speedup vs baseline: 1.2895x; 1.2895x over previous
//
#include <hip/hip_runtime.h>
#include <hip/hip_fp16.h>
#include <math.h>

#define N_NODES 200000
#define N_EDGES 6400000
#define F_INF   512
#define HID     16
#define NCLS    7

#define NPB      256                               // nodes per bucket
#define NBUCKET  ((N_NODES + NPB - 1) / NPB)       // 782
#define CHUNK    16384
#define NBLKE    ((N_EDGES + CHUNK - 1) / CHUNK)   // 391
#define STAGE_CAP 9216                             // mean 8192, sigma~90 -> 11 sigma headroom

#define TMR  256     // rows per block in gemm1
#define KCH  32      // K-chunk (floats)
#define XSTR 33      // LDS row stride: bank = (row + k) % 32 -> 2-way on wave64 = free

// ======================= pack W1|root1 -> interleaved Wc[512][48] =======================
// Wc[k][3c+0]=W1[0][k][c], Wc[k][3c+1]=W1[1][k][c], Wc[k][3c+2]=root1[k][c]
__global__ __launch_bounds__(256) void packW_kernel(
    const float* __restrict__ W1, const float* __restrict__ root1,
    float* __restrict__ Wc) {
    int t = blockIdx.x * 256 + threadIdx.x;     // 8192 = 512*16
    if (t >= F_INF * HID) return;
    int k = t >> 4, c = t & 15;
    Wc[k * 48 + 3 * c + 0] = W1[k * HID + c];
    Wc[k * 48 + 3 * c + 1] = W1[F_INF * HID + k * HID + c];
    Wc[k * 48 + 3 * c + 2] = root1[k * HID + c];
}

// ======================= layer 1 GEMM: row-per-thread, LDS-staged x, SGPR weights ======
// hbufH[n*16+c] = half2(h0_c, h1_c) ; rbufH[n*16+c] = half(root contribution)
__global__ __launch_bounds__(256) void gemm1_kernel(
    const float* __restrict__ x, const float* __restrict__ Wc,
    __half2* __restrict__ hbufH, __half* __restrict__ rbufH) {
    __shared__ float xs[TMR * XSTR];             // 33.8 KB
    int tid  = threadIdx.x;
    int lane = tid & 63, w = tid >> 6;
    int rowBase = blockIdx.x * TMR;
    int myRow = rowBase + tid;
    float acc[48];
    #pragma unroll
    for (int j = 0; j < 48; ++j) acc[j] = 0.f;

    for (int ch = 0; ch < F_INF / KCH; ++ch) {   // 16 chunks
        __syncthreads();                         // prev-chunk reads done
        // stage: wave w stages rows w*64 .. w*64+63 (8 rows x 128B per instr, coalesced)
        #pragma unroll
        for (int i = 0; i < 8; ++i) {
            int rr = w * 64 + i * 8 + (lane >> 3);
            int f4 = lane & 7;
            int grow = rowBase + rr;
            if (grow > N_NODES - 1) grow = N_NODES - 1;     // tail clamp (safe re-read)
            float4 v = *(const float4*)(x + (size_t)grow * F_INF + ch * KCH + f4 * 4);
            int bi = rr * XSTR + f4 * 4;
            xs[bi + 0] = v.x; xs[bi + 1] = v.y; xs[bi + 2] = v.z; xs[bi + 3] = v.w;
        }
        __syncthreads();
        const float* __restrict__ wkc = Wc + (size_t)ch * KCH * 48;
        #pragma unroll 4
        for (int k = 0; k < KCH; ++k) {
            float xv = xs[tid * XSTR + k];       // conflict-free (2 lanes/bank)
            const float* wk = wkc + k * 48;      // wave-uniform -> s_load
            #pragma unroll
            for (int j = 0; j < 48; ++j)
                acc[j] = fmaf(xv, wk[j], acc[j]);
        }
    }
    if (myRow >= N_NODES) return;
    __half2* hb = hbufH + (size_t)myRow * HID;
    __half*  rb = rbufH + (size_t)myRow * HID;
    #pragma unroll
    for (int c = 0; c < HID; ++c) {
        hb[c] = __floats2half2_rn(acc[3 * c + 0], acc[3 * c + 1]);
        rb[c] = __float2half(acc[3 * c + 2]);
    }
}

// ======================= P1: per-block bucket histogram =======================
__global__ __launch_bounds__(256) void p1_bincount(const int* __restrict__ dst,
                                                   int* __restrict__ blockOff) {
    __shared__ int hist[NBUCKET];
    int tid = threadIdx.x;
    for (int i = tid; i < NBUCKET; i += 256) hist[i] = 0;
    __syncthreads();
    size_t base = (size_t)blockIdx.x * CHUNK;
    for (int i = 0; i < CHUNK / 256; ++i) {
        size_t e = base + (size_t)i * 256 + tid;
        if (e < N_EDGES) atomicAdd(&hist[dst[e] >> 8], 1);
    }
    __syncthreads();
    for (int i = tid; i < NBUCKET; i += 256)
        blockOff[(size_t)i * NBLKE + blockIdx.x] = hist[i];
}

// ======================= P2a: per-bucket scan over blocks =======================
__global__ __launch_bounds__(256) void p2a_kernel(int* __restrict__ blockOff,
                                                  int* __restrict__ bucketTotal) {
    __shared__ int wsum[4];
    int b = blockIdx.x, tid = threadIdx.x;
    size_t rowb = (size_t)b * NBLKE;
    int i0 = tid * 2, i1 = i0 + 1;
    int v0 = (i0 < NBLKE) ? blockOff[rowb + i0] : 0;
    int v1 = (i1 < NBLKE) ? blockOff[rowb + i1] : 0;
    int s = v0 + v1;
    int lane = tid & 63, wid = tid >> 6;
    int incl = s;
    #pragma unroll
    for (int o = 1; o < 64; o <<= 1) {
        int t = __shfl_up(incl, o, 64);
        if (lane >= o) incl += t;
    }
    if (lane == 63) wsum[wid] = incl;
    __syncthreads();
    int woff = 0;
    for (int w = 0; w < wid; ++w) woff += wsum[w];
    int excl = woff + incl - s;
    if (i0 < NBLKE) blockOff[rowb + i0] = excl;
    if (i1 < NBLKE) blockOff[rowb + i1] = excl + v0;
    if (tid == 255) bucketTotal[b] = woff + incl;
}

// ======================= P2b: scan bucket totals -> bucketStart =======================
__global__ __launch_bounds__(256) void p2b_kernel(const int* __restrict__ bucketTotal,
                                                  int* __restrict__ bucketStart,
                                                  int* __restrict__ rowptr) {
    __shared__ int wsum[4];
    int tid = threadIdx.x;
    int base = tid * 4;
    int v[4]; int s = 0;
    #pragma unroll
    for (int q = 0; q < 4; ++q) {
        int idx = base + q;
        v[q] = (idx < NBUCKET) ? bucketTotal[idx] : 0;
        s += v[q];
    }
    int lane = tid & 63, wid = tid >> 6;
    int incl = s;
    #pragma unroll
    for (int o = 1; o < 64; o <<= 1) {
        int t = __shfl_up(incl, o, 64);
        if (lane >= o) incl += t;
    }
    if (lane == 63) wsum[wid] = incl;
    __syncthreads();
    int woff = 0;
    for (int w = 0; w < wid; ++w) woff += wsum[w];
    int run = woff + incl - s;
    #pragma unroll
    for (int q = 0; q < 4; ++q) {
        int idx = base + q;
        if (idx < NBUCKET) bucketStart[idx] = run;
        run += v[q];
    }
    if (tid == 0) rowptr[N_NODES] = N_EDGES;
}

// ======================= P3: binned scatter of payload =======================
__global__ __launch_bounds__(256) void p3_binscatter(
    const int* __restrict__ dst, const int* __restrict__ src,
    const float* __restrict__ eattr,
    const int* __restrict__ blockOff, const int* __restrict__ bucketStart,
    unsigned int* __restrict__ metaArr, __half* __restrict__ wHarr) {
    __shared__ int cur[NBUCKET];
    int tid = threadIdx.x;
    for (int i = tid; i < NBUCKET; i += 256)
        cur[i] = bucketStart[i] + blockOff[(size_t)i * NBLKE + blockIdx.x];
    __syncthreads();
    size_t base = (size_t)blockIdx.x * CHUNK;
    for (int i = 0; i < CHUNK / 256; ++i) {
        size_t e = base + (size_t)i * 256 + tid;
        if (e < N_EDGES) {
            int d = dst[e];
            int b = d >> 8;
            int slot = atomicAdd(&cur[b], 1);
            unsigned int meta = ((unsigned int)(d & 255) << 18) | (unsigned int)src[e];
            float w = fminf(fmaxf(eattr[e], 0.f), 1.f);
            metaArr[slot] = meta;
            wHarr[slot] = __float2half(w);
        }
    }
}

// ======================= P4: per-bucket fine sort -> CSR + rowptr =======================
__global__ __launch_bounds__(256) void p4_buildcsr(
    const int* __restrict__ bucketStart, const int* __restrict__ bucketTotal,
    unsigned int* __restrict__ metaArr, __half* __restrict__ wHarr,
    int* __restrict__ rowptr) {
    __shared__ unsigned int stageM[STAGE_CAP];
    __shared__ __half stageW[STAGE_CAP];
    __shared__ int hist[NPB];
    __shared__ int wsum[4];
    int b = blockIdx.x, tid = threadIdx.x;
    int start = bucketStart[b];
    int count = bucketTotal[b];
    int nn = min(NPB, N_NODES - b * NPB);
    hist[tid] = 0;
    __syncthreads();
    for (int i = tid; i < count; i += 256) {
        unsigned int m = metaArr[start + i];
        stageM[i] = m;
        stageW[i] = wHarr[start + i];
        atomicAdd(&hist[m >> 18], 1);
    }
    __syncthreads();
    int v = hist[tid];
    int lane = tid & 63, wid = tid >> 6;
    int incl = v;
    #pragma unroll
    for (int o = 1; o < 64; o <<= 1) {
        int t = __shfl_up(incl, o, 64);
        if (lane >= o) incl += t;
    }
    if (lane == 63) wsum[wid] = incl;
    __syncthreads();
    int woff = 0;
    for (int w = 0; w < wid; ++w) woff += wsum[w];
    int excl = woff + incl - v;
    if (tid < nn) rowptr[b * NPB + tid] = start + excl;
    __syncthreads();
    hist[tid] = excl;
    __syncthreads();
    for (int i = tid; i < count; i += 256) {
        unsigned int m = stageM[i];
        int local = (int)(m >> 18);
        int pos = start + atomicAdd(&hist[local], 1);
        metaArr[pos] = m & 0x3FFFFu;
        wHarr[pos] = stageW[i];
    }
}

// ======================= agg1: gather-aggregate + ELU (16 lanes/node) =======================
__global__ __launch_bounds__(256) void agg1_kernel(
    const unsigned int* __restrict__ metaArr, const __half* __restrict__ wHarr,
    const int* __restrict__ rowptr, const __half2* __restrict__ hbufH,
    __half* __restrict__ rbufH, const float* __restrict__ bias1) {
    int t = blockIdx.x * 256 + threadIdx.x;
    int n = t >> 4;
    if (n >= N_NODES) return;
    int c = t & 15;
    int beg = rowptr[n], end = rowptr[n + 1];
    float acc = 0.f;
    for (int p = beg; p < end; ++p) {
        int s = (int)metaArr[p];
        float b1 = __half2float(wHarr[p]);
        float2 h = __half22float2(hbufH[(size_t)s * HID + c]);
        acc += fmaf(b1, h.y - h.x, h.x);
    }
    float invd = 1.0f / fmaxf((float)(end - beg), 1.0f);
    float r = __half2float(rbufH[(size_t)n * HID + c]);
    float vv = fmaf(acc, invd, r) + bias1[c];
    float hv = vv > 0.f ? vv : expm1f(vv);
    rbufH[(size_t)n * HID + c] = __float2half(hv);
}

// ======================= node1b: tiny layer-2 transforms =======================
__global__ __launch_bounds__(256) void node1b_kernel(
    const __half* __restrict__ rbufH, const float* __restrict__ W2,
    const float* __restrict__ root2,
    __half2* __restrict__ h2buf, float* __restrict__ r2buf) {
    int n = blockIdx.x * 256 + threadIdx.x;
    if (n >= N_NODES) return;
    float h[HID];
    #pragma unroll
    for (int k = 0; k < HID; ++k) h[k] = __half2float(rbufH[(size_t)n * HID + k]);
    float o0[NCLS], o1[NCLS], orr[NCLS];
    #pragma unroll
    for (int j = 0; j < NCLS; ++j) { o0[j] = 0.f; o1[j] = 0.f; orr[j] = 0.f; }
    const float* __restrict__ W2b = W2 + HID * NCLS;
    #pragma unroll
    for (int k = 0; k < HID; ++k) {
        #pragma unroll
        for (int j = 0; j < NCLS; ++j) {
            o0[j]  = fmaf(h[k], W2 [k * NCLS + j], o0[j]);
            o1[j]  = fmaf(h[k], W2b[k * NCLS + j], o1[j]);
            orr[j] = fmaf(h[k], root2[k * NCLS + j], orr[j]);
        }
    }
    __half2* hb = h2buf + (size_t)n * 8;
    float*   r2 = r2buf + (size_t)n * 8;
    #pragma unroll
    for (int j = 0; j < NCLS; ++j) {
        hb[j] = __floats2half2_rn(o0[j], o1[j]);
        r2[j] = orr[j];
    }
    hb[7] = __floats2half2_rn(0.f, 0.f);
    r2[7] = 0.f;
}

// ======================= agg2: gather-aggregate + log_softmax (8 lanes/node) ==========
__global__ __launch_bounds__(256) void agg2_kernel(
    const unsigned int* __restrict__ metaArr, const __half* __restrict__ wHarr,
    const int* __restrict__ rowptr, const __half2* __restrict__ h2buf,
    const float* __restrict__ r2buf, const float* __restrict__ bias2,
    float* __restrict__ out) {
    int t = blockIdx.x * 256 + threadIdx.x;
    int n = t >> 3;
    if (n >= N_NODES) return;
    int j = t & 7;
    int beg = rowptr[n], end = rowptr[n + 1];
    float acc = 0.f;
    for (int p = beg; p < end; ++p) {
        int s = (int)metaArr[p];
        float b1 = __half2float(wHarr[p]);
        float2 m = __half22float2(h2buf[(size_t)s * 8 + j]);
        acc += fmaf(b1, m.y - m.x, m.x);
    }
    float invd = 1.0f / fmaxf((float)(end - beg), 1.0f);
    float v = fmaf(acc, invd, r2buf[(size_t)n * 8 + j]) + ((j < NCLS) ? bias2[j] : 0.f);
    if (j == NCLS) v = -INFINITY;
    float mx = v;
    mx = fmaxf(mx, __shfl_xor(mx, 1, 8));
    mx = fmaxf(mx, __shfl_xor(mx, 2, 8));
    mx = fmaxf(mx, __shfl_xor(mx, 4, 8));
    float ex = expf(v - mx);
    float sm = ex;
    sm += __shfl_xor(sm, 1, 8);
    sm += __shfl_xor(sm, 2, 8);
    sm += __shfl_xor(sm, 4, 8);
    float lse = mx + logf(sm);
    if (j < NCLS) out[(size_t)n * NCLS + j] = v - lse;
}

extern "C" void kernel_launch(void* const* d_in, const int* in_sizes, int n_in,
                              void* d_out, int out_size, void* d_ws, size_t ws_size,
                              hipStream_t stream) {
    const float* x     = (const float*)d_in[0];
    const float* eattr = (const float*)d_in[1];
    const int*   src   = (const int*)d_in[2];
    const int*   dst   = (const int*)d_in[3];
    const float* W1    = (const float*)d_in[4];
    const float* root1 = (const float*)d_in[5];
    const float* bias1 = (const float*)d_in[6];
    const float* W2    = (const float*)d_in[7];
    const float* root2 = (const float*)d_in[8];
    const float* bias2 = (const float*)d_in[9];
    float* out = (float*)d_out;

    // ---------- workspace layout (~60 MB) ----------
    char* wp = (char*)d_ws;
    unsigned int* metaArr = (unsigned int*)wp;  wp += (size_t)N_EDGES * 4;           // 25.6 MB
    __half*       wHarr   = (__half*)wp;        wp += (size_t)N_EDGES * 2;           // 12.8 MB
    int* blockOff    = (int*)wp;                wp += (size_t)NBUCKET * NBLKE * 4;   // 1.22 MB
    int* bucketTotal = (int*)wp;                wp += 1024 * 4;
    int* bucketStart = (int*)wp;                wp += 1024 * 4;
    int* rowptr      = (int*)wp;                wp += (size_t)(N_NODES + 4) * 4;     // 0.8 MB
    float* Wc        = (float*)wp;              wp += (size_t)F_INF * 48 * 4;        // 98 KB
    __half2* hbufH   = (__half2*)wp;            wp += (size_t)N_NODES * HID * 4;     // 12.8 MB
    __half*  rbufH   = (__half*)wp;             wp += (size_t)N_NODES * HID * 2;     // 6.4 MB
    // aliases: hbufH region is dead after agg1
    __half2* h2buf = hbufH;                                          // N*8 half2
    float*   r2buf = (float*)(hbufH + (size_t)N_NODES * 8);          // N*8 f32

    const int node_blocks = (N_NODES + 255) / 256;  // 782

    hipLaunchKernelGGL(packW_kernel, dim3((F_INF * HID + 255) / 256), dim3(256), 0, stream,
                       W1, root1, Wc);
    hipLaunchKernelGGL(gemm1_kernel, dim3((N_NODES + TMR - 1) / TMR), dim3(256), 0, stream,
                       x, Wc, hbufH, rbufH);
    hipLaunchKernelGGL(p1_bincount, dim3(NBLKE), dim3(256), 0, stream, dst, blockOff);
    hipLaunchKernelGGL(p2a_kernel, dim3(NBUCKET), dim3(256), 0, stream,
                       blockOff, bucketTotal);
    hipLaunchKernelGGL(p2b_kernel, dim3(1), dim3(256), 0, stream,
                       bucketTotal, bucketStart, rowptr);
    hipLaunchKernelGGL(p3_binscatter, dim3(NBLKE), dim3(256), 0, stream,
                       dst, src, eattr, blockOff, bucketStart, metaArr, wHarr);
    hipLaunchKernelGGL(p4_buildcsr, dim3(NBUCKET), dim3(256), 0, stream,
                       bucketStart, bucketTotal, metaArr, wHarr, rowptr);
    hipLaunchKernelGGL(agg1_kernel, dim3((N_NODES * 16 + 255) / 256), dim3(256), 0, stream,
                       metaArr, wHarr, rowptr, hbufH, rbufH, bias1);
    hipLaunchKernelGGL(node1b_kernel, dim3(node_blocks), dim3(256), 0, stream,
                       rbufH, W2, root2, h2buf, r2buf);
    hipLaunchKernelGGL(agg2_kernel, dim3((N_NODES * 8 + 255) / 256), dim3(256), 0, stream,
                       metaArr, wHarr, rowptr, h2buf, r2buf, bias2, out);
}

// Round 8
// 1021.771 us; speedup vs baseline: 1.2971x; 1.0059x over previous
//
#include <hip/hip_runtime.h>
#include <hip/hip_fp16.h>
#include <math.h>

#define N_NODES 200000
#define N_EDGES 6400000
#define F_INF   512
#define HID     16
#define NCLS    7

#define NPB      256                               // nodes per bucket
#define NBUCKET  ((N_NODES + NPB - 1) / NPB)       // 782
#define CHUNK    16384
#define NBLKE    ((N_EDGES + CHUNK - 1) / CHUNK)   // 391
#define STAGE_CAP 9216                             // mean 8192, sigma~90 -> 11 sigma headroom

#define TMR  256     // rows per block in gemm1
#define KCH  16      // K-chunk (floats)
#define NCH  (F_INF / KCH)                         // 32 chunks
#define XSTR 17      // LDS row stride: odd -> 2 lanes/bank on reads & writes = free

// ======================= pack W1|root1 -> interleaved Wc[512][48] =======================
// Wc[k][3c+0]=W1[0][k][c], Wc[k][3c+1]=W1[1][k][c], Wc[k][3c+2]=root1[k][c]
__global__ __launch_bounds__(256) void packW_kernel(
    const float* __restrict__ W1, const float* __restrict__ root1,
    float* __restrict__ Wc) {
    int t = blockIdx.x * 256 + threadIdx.x;     // 8192 = 512*16
    if (t >= F_INF * HID) return;
    int k = t >> 4, c = t & 15;
    Wc[k * 48 + 3 * c + 0] = W1[k * HID + c];
    Wc[k * 48 + 3 * c + 1] = W1[F_INF * HID + k * HID + c];
    Wc[k * 48 + 3 * c + 2] = root1[k * HID + c];
}

// ======================= layer 1 GEMM: row-per-thread, double-buffered LDS ======
// hbufH[n*16+c] = half2(h0_c, h1_c) ; rbufH[n*16+c] = half(root contribution)
__global__ __launch_bounds__(256) void gemm1_kernel(
    const float* __restrict__ x, const float* __restrict__ Wc,
    __half2* __restrict__ hbufH, __half* __restrict__ rbufH) {
    __shared__ float xs[2][TMR * XSTR];          // 2 x 17.4 KB = 34.8 KB
    int tid = threadIdx.x;
    int myRow = blockIdx.x * TMR + tid;
    int rowC = myRow < N_NODES ? myRow : N_NODES - 1;   // clamped for loads
    const float* __restrict__ xrow = x + (size_t)rowC * F_INF;

    float acc[48];
    #pragma unroll
    for (int j = 0; j < 48; ++j) acc[j] = 0.f;

    float4 st0, st1, st2, st3;
    // prologue: load + stage chunk 0
    {
        const float4* p = (const float4*)(xrow);
        st0 = p[0]; st1 = p[1]; st2 = p[2]; st3 = p[3];
        float* d = &xs[0][tid * XSTR];
        d[0]=st0.x; d[1]=st0.y; d[2]=st0.z; d[3]=st0.w;
        d[4]=st1.x; d[5]=st1.y; d[6]=st1.z; d[7]=st1.w;
        d[8]=st2.x; d[9]=st2.y; d[10]=st2.z; d[11]=st2.w;
        d[12]=st3.x; d[13]=st3.y; d[14]=st3.z; d[15]=st3.w;
    }
    __syncthreads();

    for (int ch = 0; ch < NCH; ++ch) {
        // issue next chunk's loads early (latency hides under compute)
        if (ch + 1 < NCH) {
            const float4* p = (const float4*)(xrow + (ch + 1) * KCH);
            st0 = p[0]; st1 = p[1]; st2 = p[2]; st3 = p[3];
        }
        // compute current chunk from LDS + wave-uniform scalar weights
        const float* __restrict__ wkc = Wc + (size_t)ch * KCH * 48;
        const float* __restrict__ xr = &xs[ch & 1][tid * XSTR];
        #pragma unroll 4
        for (int k = 0; k < KCH; ++k) {
            float xv = xr[k];
            const float* wk = wkc + k * 48;      // wave-uniform -> s_load
            #pragma unroll
            for (int j = 0; j < 48; ++j)
                acc[j] = fmaf(xv, wk[j], acc[j]);
        }
        __syncthreads();                         // all waves done reading buf[ch&1]
        if (ch + 1 < NCH) {
            float* d = &xs[(ch + 1) & 1][tid * XSTR];
            d[0]=st0.x; d[1]=st0.y; d[2]=st0.z; d[3]=st0.w;
            d[4]=st1.x; d[5]=st1.y; d[6]=st1.z; d[7]=st1.w;
            d[8]=st2.x; d[9]=st2.y; d[10]=st2.z; d[11]=st2.w;
            d[12]=st3.x; d[13]=st3.y; d[14]=st3.z; d[15]=st3.w;
            __syncthreads();                     // staged data visible before next compute
        }
    }

    if (myRow >= N_NODES) return;
    __half2* hb = hbufH + (size_t)myRow * HID;
    __half*  rb = rbufH + (size_t)myRow * HID;
    #pragma unroll
    for (int c = 0; c < HID; ++c) {
        hb[c] = __floats2half2_rn(acc[3 * c + 0], acc[3 * c + 1]);
        rb[c] = __float2half(acc[3 * c + 2]);
    }
}

// ======================= P1: per-block bucket histogram =======================
__global__ __launch_bounds__(256) void p1_bincount(const int* __restrict__ dst,
                                                   int* __restrict__ blockOff) {
    __shared__ int hist[NBUCKET];
    int tid = threadIdx.x;
    for (int i = tid; i < NBUCKET; i += 256) hist[i] = 0;
    __syncthreads();
    size_t base = (size_t)blockIdx.x * CHUNK;
    for (int i = 0; i < CHUNK / 256; ++i) {
        size_t e = base + (size_t)i * 256 + tid;
        if (e < N_EDGES) atomicAdd(&hist[dst[e] >> 8], 1);
    }
    __syncthreads();
    for (int i = tid; i < NBUCKET; i += 256)
        blockOff[(size_t)i * NBLKE + blockIdx.x] = hist[i];
}

// ======================= P2a: per-bucket scan over blocks =======================
__global__ __launch_bounds__(256) void p2a_kernel(int* __restrict__ blockOff,
                                                  int* __restrict__ bucketTotal) {
    __shared__ int wsum[4];
    int b = blockIdx.x, tid = threadIdx.x;
    size_t rowb = (size_t)b * NBLKE;
    int i0 = tid * 2, i1 = i0 + 1;
    int v0 = (i0 < NBLKE) ? blockOff[rowb + i0] : 0;
    int v1 = (i1 < NBLKE) ? blockOff[rowb + i1] : 0;
    int s = v0 + v1;
    int lane = tid & 63, wid = tid >> 6;
    int incl = s;
    #pragma unroll
    for (int o = 1; o < 64; o <<= 1) {
        int t = __shfl_up(incl, o, 64);
        if (lane >= o) incl += t;
    }
    if (lane == 63) wsum[wid] = incl;
    __syncthreads();
    int woff = 0;
    for (int w = 0; w < wid; ++w) woff += wsum[w];
    int excl = woff + incl - s;
    if (i0 < NBLKE) blockOff[rowb + i0] = excl;
    if (i1 < NBLKE) blockOff[rowb + i1] = excl + v0;
    if (tid == 255) bucketTotal[b] = woff + incl;
}

// ======================= P2b: scan bucket totals -> bucketStart =======================
__global__ __launch_bounds__(256) void p2b_kernel(const int* __restrict__ bucketTotal,
                                                  int* __restrict__ bucketStart,
                                                  int* __restrict__ rowptr) {
    __shared__ int wsum[4];
    int tid = threadIdx.x;
    int base = tid * 4;
    int v[4]; int s = 0;
    #pragma unroll
    for (int q = 0; q < 4; ++q) {
        int idx = base + q;
        v[q] = (idx < NBUCKET) ? bucketTotal[idx] : 0;
        s += v[q];
    }
    int lane = tid & 63, wid = tid >> 6;
    int incl = s;
    #pragma unroll
    for (int o = 1; o < 64; o <<= 1) {
        int t = __shfl_up(incl, o, 64);
        if (lane >= o) incl += t;
    }
    if (lane == 63) wsum[wid] = incl;
    __syncthreads();
    int woff = 0;
    for (int w = 0; w < wid; ++w) woff += wsum[w];
    int run = woff + incl - s;
    #pragma unroll
    for (int q = 0; q < 4; ++q) {
        int idx = base + q;
        if (idx < NBUCKET) bucketStart[idx] = run;
        run += v[q];
    }
    if (tid == 0) rowptr[N_NODES] = N_EDGES;
}

// ======================= P3: binned scatter of payload =======================
__global__ __launch_bounds__(256) void p3_binscatter(
    const int* __restrict__ dst, const int* __restrict__ src,
    const float* __restrict__ eattr,
    const int* __restrict__ blockOff, const int* __restrict__ bucketStart,
    unsigned int* __restrict__ metaArr, __half* __restrict__ wHarr) {
    __shared__ int cur[NBUCKET];
    int tid = threadIdx.x;
    for (int i = tid; i < NBUCKET; i += 256)
        cur[i] = bucketStart[i] + blockOff[(size_t)i * NBLKE + blockIdx.x];
    __syncthreads();
    size_t base = (size_t)blockIdx.x * CHUNK;
    for (int i = 0; i < CHUNK / 256; ++i) {
        size_t e = base + (size_t)i * 256 + tid;
        if (e < N_EDGES) {
            int d = dst[e];
            int b = d >> 8;
            int slot = atomicAdd(&cur[b], 1);
            unsigned int meta = ((unsigned int)(d & 255) << 18) | (unsigned int)src[e];
            float w = fminf(fmaxf(eattr[e], 0.f), 1.f);
            metaArr[slot] = meta;
            wHarr[slot] = __float2half(w);
        }
    }
}

// ======================= P4: per-bucket fine sort -> CSR + rowptr =======================
__global__ __launch_bounds__(256) void p4_buildcsr(
    const int* __restrict__ bucketStart, const int* __restrict__ bucketTotal,
    unsigned int* __restrict__ metaArr, __half* __restrict__ wHarr,
    int* __restrict__ rowptr) {
    __shared__ unsigned int stageM[STAGE_CAP];
    __shared__ __half stageW[STAGE_CAP];
    __shared__ int hist[NPB];
    __shared__ int wsum[4];
    int b = blockIdx.x, tid = threadIdx.x;
    int start = bucketStart[b];
    int count = bucketTotal[b];
    int nn = min(NPB, N_NODES - b * NPB);
    hist[tid] = 0;
    __syncthreads();
    for (int i = tid; i < count; i += 256) {
        unsigned int m = metaArr[start + i];
        stageM[i] = m;
        stageW[i] = wHarr[start + i];
        atomicAdd(&hist[m >> 18], 1);
    }
    __syncthreads();
    int v = hist[tid];
    int lane = tid & 63, wid = tid >> 6;
    int incl = v;
    #pragma unroll
    for (int o = 1; o < 64; o <<= 1) {
        int t = __shfl_up(incl, o, 64);
        if (lane >= o) incl += t;
    }
    if (lane == 63) wsum[wid] = incl;
    __syncthreads();
    int woff = 0;
    for (int w = 0; w < wid; ++w) woff += wsum[w];
    int excl = woff + incl - v;
    if (tid < nn) rowptr[b * NPB + tid] = start + excl;
    __syncthreads();
    hist[tid] = excl;
    __syncthreads();
    for (int i = tid; i < count; i += 256) {
        unsigned int m = stageM[i];
        int local = (int)(m >> 18);
        int pos = start + atomicAdd(&hist[local], 1);
        metaArr[pos] = m & 0x3FFFFu;
        wHarr[pos] = stageW[i];
    }
}

// ======================= agg1: gather-aggregate + ELU (16 lanes/node) =======================
__global__ __launch_bounds__(256) void agg1_kernel(
    const unsigned int* __restrict__ metaArr, const __half* __restrict__ wHarr,
    const int* __restrict__ rowptr, const __half2* __restrict__ hbufH,
    __half* __restrict__ rbufH, const float* __restrict__ bias1) {
    int t = blockIdx.x * 256 + threadIdx.x;
    int n = t >> 4;
    if (n >= N_NODES) return;
    int c = t & 15;
    int beg = rowptr[n], end = rowptr[n + 1];
    float acc = 0.f;
    for (int p = beg; p < end; ++p) {
        int s = (int)metaArr[p];
        float b1 = __half2float(wHarr[p]);
        float2 h = __half22float2(hbufH[(size_t)s * HID + c]);
        acc += fmaf(b1, h.y - h.x, h.x);
    }
    float invd = 1.0f / fmaxf((float)(end - beg), 1.0f);
    float r = __half2float(rbufH[(size_t)n * HID + c]);
    float vv = fmaf(acc, invd, r) + bias1[c];
    float hv = vv > 0.f ? vv : expm1f(vv);
    rbufH[(size_t)n * HID + c] = __float2half(hv);
}

// ======================= node1b: tiny layer-2 transforms =======================
__global__ __launch_bounds__(256) void node1b_kernel(
    const __half* __restrict__ rbufH, const float* __restrict__ W2,
    const float* __restrict__ root2,
    __half2* __restrict__ h2buf, float* __restrict__ r2buf) {
    int n = blockIdx.x * 256 + threadIdx.x;
    if (n >= N_NODES) return;
    float h[HID];
    #pragma unroll
    for (int k = 0; k < HID; ++k) h[k] = __half2float(rbufH[(size_t)n * HID + k]);
    float o0[NCLS], o1[NCLS], orr[NCLS];
    #pragma unroll
    for (int j = 0; j < NCLS; ++j) { o0[j] = 0.f; o1[j] = 0.f; orr[j] = 0.f; }
    const float* __restrict__ W2b = W2 + HID * NCLS;
    #pragma unroll
    for (int k = 0; k < HID; ++k) {
        #pragma unroll
        for (int j = 0; j < NCLS; ++j) {
            o0[j]  = fmaf(h[k], W2 [k * NCLS + j], o0[j]);
            o1[j]  = fmaf(h[k], W2b[k * NCLS + j], o1[j]);
            orr[j] = fmaf(h[k], root2[k * NCLS + j], orr[j]);
        }
    }
    __half2* hb = h2buf + (size_t)n * 8;
    float*   r2 = r2buf + (size_t)n * 8;
    #pragma unroll
    for (int j = 0; j < NCLS; ++j) {
        hb[j] = __floats2half2_rn(o0[j], o1[j]);
        r2[j] = orr[j];
    }
    hb[7] = __floats2half2_rn(0.f, 0.f);
    r2[7] = 0.f;
}

// ======================= agg2: gather-aggregate + log_softmax (8 lanes/node) ==========
__global__ __launch_bounds__(256) void agg2_kernel(
    const unsigned int* __restrict__ metaArr, const __half* __restrict__ wHarr,
    const int* __restrict__ rowptr, const __half2* __restrict__ h2buf,
    const float* __restrict__ r2buf, const float* __restrict__ bias2,
    float* __restrict__ out) {
    int t = blockIdx.x * 256 + threadIdx.x;
    int n = t >> 3;
    if (n >= N_NODES) return;
    int j = t & 7;
    int beg = rowptr[n], end = rowptr[n + 1];
    float acc = 0.f;
    for (int p = beg; p < end; ++p) {
        int s = (int)metaArr[p];
        float b1 = __half2float(wHarr[p]);
        float2 m = __half22float2(h2buf[(size_t)s * 8 + j]);
        acc += fmaf(b1, m.y - m.x, m.x);
    }
    float invd = 1.0f / fmaxf((float)(end - beg), 1.0f);
    float v = fmaf(acc, invd, r2buf[(size_t)n * 8 + j]) + ((j < NCLS) ? bias2[j] : 0.f);
    if (j == NCLS) v = -INFINITY;
    float mx = v;
    mx = fmaxf(mx, __shfl_xor(mx, 1, 8));
    mx = fmaxf(mx, __shfl_xor(mx, 2, 8));
    mx = fmaxf(mx, __shfl_xor(mx, 4, 8));
    float ex = expf(v - mx);
    float sm = ex;
    sm += __shfl_xor(sm, 1, 8);
    sm += __shfl_xor(sm, 2, 8);
    sm += __shfl_xor(sm, 4, 8);
    float lse = mx + logf(sm);
    if (j < NCLS) out[(size_t)n * NCLS + j] = v - lse;
}

extern "C" void kernel_launch(void* const* d_in, const int* in_sizes, int n_in,
                              void* d_out, int out_size, void* d_ws, size_t ws_size,
                              hipStream_t stream) {
    const float* x     = (const float*)d_in[0];
    const float* eattr = (const float*)d_in[1];
    const int*   src   = (const int*)d_in[2];
    const int*   dst   = (const int*)d_in[3];
    const float* W1    = (const float*)d_in[4];
    const float* root1 = (const float*)d_in[5];
    const float* bias1 = (const float*)d_in[6];
    const float* W2    = (const float*)d_in[7];
    const float* root2 = (const float*)d_in[8];
    const float* bias2 = (const float*)d_in[9];
    float* out = (float*)d_out;

    // ---------- workspace layout (~60 MB) ----------
    char* wp = (char*)d_ws;
    unsigned int* metaArr = (unsigned int*)wp;  wp += (size_t)N_EDGES * 4;           // 25.6 MB
    __half*       wHarr   = (__half*)wp;        wp += (size_t)N_EDGES * 2;           // 12.8 MB
    int* blockOff    = (int*)wp;                wp += (size_t)NBUCKET * NBLKE * 4;   // 1.22 MB
    int* bucketTotal = (int*)wp;                wp += 1024 * 4;
    int* bucketStart = (int*)wp;                wp += 1024 * 4;
    int* rowptr      = (int*)wp;                wp += (size_t)(N_NODES + 4) * 4;     // 0.8 MB
    float* Wc        = (float*)wp;              wp += (size_t)F_INF * 48 * 4;        // 98 KB
    __half2* hbufH   = (__half2*)wp;            wp += (size_t)N_NODES * HID * 4;     // 12.8 MB
    __half*  rbufH   = (__half*)wp;             wp += (size_t)N_NODES * HID * 2;     // 6.4 MB
    // aliases: hbufH region is dead after agg1
    __half2* h2buf = hbufH;                                          // N*8 half2
    float*   r2buf = (float*)(hbufH + (size_t)N_NODES * 8);          // N*8 f32

    const int node_blocks = (N_NODES + 255) / 256;  // 782

    hipLaunchKernelGGL(packW_kernel, dim3((F_INF * HID + 255) / 256), dim3(256), 0, stream,
                       W1, root1, Wc);
    hipLaunchKernelGGL(gemm1_kernel, dim3((N_NODES + TMR - 1) / TMR), dim3(256), 0, stream,
                       x, Wc, hbufH, rbufH);
    hipLaunchKernelGGL(p1_bincount, dim3(NBLKE), dim3(256), 0, stream, dst, blockOff);
    hipLaunchKernelGGL(p2a_kernel, dim3(NBUCKET), dim3(256), 0, stream,
                       blockOff, bucketTotal);
    hipLaunchKernelGGL(p2b_kernel, dim3(1), dim3(256), 0, stream,
                       bucketTotal, bucketStart, rowptr);
    hipLaunchKernelGGL(p3_binscatter, dim3(NBLKE), dim3(256), 0, stream,
                       dst, src, eattr, blockOff, bucketStart, metaArr, wHarr);
    hipLaunchKernelGGL(p4_buildcsr, dim3(NBUCKET), dim3(256), 0, stream,
                       bucketStart, bucketTotal, metaArr, wHarr, rowptr);
    hipLaunchKernelGGL(agg1_kernel, dim3((N_NODES * 16 + 255) / 256), dim3(256), 0, stream,
                       metaArr, wHarr, rowptr, hbufH, rbufH, bias1);
    hipLaunchKernelGGL(node1b_kernel, dim3(node_blocks), dim3(256), 0, stream,
                       rbufH, W2, root2, h2buf, r2buf);
    hipLaunchKernelGGL(agg2_kernel, dim3((N_NODES * 8 + 255) / 256), dim3(256), 0, stream,
                       metaArr, wHarr, rowptr, h2buf, r2buf, bias2, out);
}

// Round 9
// 791.550 us; speedup vs baseline: 1.6743x; 1.2908x over previous
//
#include <hip/hip_runtime.h>
#include <hip/hip_fp16.h>
#include <math.h>

#define N_NODES 200000
#define N_EDGES 6400000
#define F_INF   512
#define HID     16
#define NCLS    7

#define NPB      256                               // nodes per bucket
#define NBUCKET  ((N_NODES + NPB - 1) / NPB)       // 782
#define CHUNK    16384
#define NBLKE    ((N_EDGES + CHUNK - 1) / CHUNK)   // 391
#define STAGE_CAP 9216                             // mean 8192, sigma~90 -> 11 sigma headroom

// ---- gemm1 (MFMA) geometry ----
#define GROWS 64     // rows per block (4 waves x 16)
#define KCHG  256    // K-chunk in fp32 elems (2 chunks of 256 = 512)
#define ASTR  264    // LDS row stride in halves (528B = 4 banks mod 32 -> uniform)

typedef _Float16 f16x8 __attribute__((ext_vector_type(8)));
typedef float    f32x4 __attribute__((ext_vector_type(4)));

// ======================= pack (W1[0]|W1[1]|root1) into MFMA B-fragment order ========
// Bf[((t*16+kk)*64+lane)*8+j] = M_t[k = kk*32+(lane>>4)*8+j][col = lane&15]
__global__ __launch_bounds__(256) void packB_kernel(
    const float* __restrict__ W1, const float* __restrict__ root1,
    __half* __restrict__ Bf) {
    int tt = blockIdx.x * 256 + threadIdx.x;    // 3*16*64 = 3072
    if (tt >= 3 * 16 * 64) return;
    int lane = tt & 63, kk = (tt >> 6) & 15, t = tt >> 10;
    int col = lane & 15;
    int kbase = kk * 32 + (lane >> 4) * 8;
    const float* __restrict__ srcm = (t == 0) ? W1
                                   : (t == 1) ? (W1 + F_INF * HID) : root1;
    #pragma unroll
    for (int j = 0; j < 8; ++j)
        Bf[(size_t)tt * 8 + j] = __float2half(srcm[(kbase + j) * HID + col]);
}

// ======================= layer 1 GEMM via MFMA =======================
// hbufH[n*16+c] = half2(h0_c, h1_c) ; rbufH[n*16+c] = half(root contribution)
__global__ __launch_bounds__(256) void gemm1_kernel(
    const float* __restrict__ x, const __half* __restrict__ Bf,
    __half2* __restrict__ hbufH, __half* __restrict__ rbufH) {
    __shared__ __half As[GROWS * ASTR];          // 33792 B
    int tid = threadIdx.x;
    int l = tid & 63, w = tid >> 6;
    int rowBase = blockIdx.x * GROWS;

    f32x4 acc0 = {0.f, 0.f, 0.f, 0.f};
    f32x4 acc1 = {0.f, 0.f, 0.f, 0.f};
    f32x4 acc2 = {0.f, 0.f, 0.f, 0.f};

    const __half* __restrict__ Arow = &As[(w * 16 + (l & 15)) * ASTR + (l >> 4) * 8];

    for (int ch = 0; ch < F_INF / KCHG; ++ch) {  // 2 chunks
        __syncthreads();                         // prev-chunk readers done
        // stage rows [16w, 16w+16): per instr one full 1KB row-chunk, coalesced
        #pragma unroll
        for (int j = 0; j < 16; ++j) {
            int row = w * 16 + j;
            float4 v = *(const float4*)(x + (size_t)(rowBase + row) * F_INF
                                          + ch * KCHG + l * 4);
            union { __half2 h2[2]; float2 f2; } u;
            u.h2[0] = __floats2half2_rn(v.x, v.y);
            u.h2[1] = __floats2half2_rn(v.z, v.w);
            *(float2*)(&As[row * ASTR + l * 4]) = u.f2;   // ds_write_b64, uniform banks
        }
        __syncthreads();
        // 8 K-steps of 16x16x32, 3 col-tiles (W1_0 | W1_1 | root1)
        #pragma unroll
        for (int kkl = 0; kkl < 8; ++kkl) {
            f16x8 a = *(const f16x8*)(Arow + kkl * 32);
            int kkg = ch * 8 + kkl;
            const __half* bp = Bf + ((size_t)kkg * 64 + l) * 8;
            f16x8 b0 = *(const f16x8*)(bp);
            f16x8 b1 = *(const f16x8*)(bp + 16 * 64 * 8);
            f16x8 b2 = *(const f16x8*)(bp + 2 * 16 * 64 * 8);
            acc0 = __builtin_amdgcn_mfma_f32_16x16x32_f16(a, b0, acc0, 0, 0, 0);
            acc1 = __builtin_amdgcn_mfma_f32_16x16x32_f16(a, b1, acc1, 0, 0, 0);
            acc2 = __builtin_amdgcn_mfma_f32_16x16x32_f16(a, b2, acc2, 0, 0, 0);
        }
    }
    // epilogue: C/D layout col=lane&15, row=(lane>>4)*4+r  [m89]
    int c = l & 15;
    int rbase = rowBase + w * 16 + (l >> 4) * 4;
    #pragma unroll
    for (int r = 0; r < 4; ++r) {
        int n = rbase + r;
        hbufH[(size_t)n * HID + c] = __floats2half2_rn(acc0[r], acc1[r]);
        rbufH[(size_t)n * HID + c] = __float2half(acc2[r]);
    }
}

// ======================= P1: per-block bucket histogram =======================
__global__ __launch_bounds__(256) void p1_bincount(const int* __restrict__ dst,
                                                   int* __restrict__ blockOff) {
    __shared__ int hist[NBUCKET];
    int tid = threadIdx.x;
    for (int i = tid; i < NBUCKET; i += 256) hist[i] = 0;
    __syncthreads();
    size_t base = (size_t)blockIdx.x * CHUNK;
    for (int i = 0; i < CHUNK / 256; ++i) {
        size_t e = base + (size_t)i * 256 + tid;
        if (e < N_EDGES) atomicAdd(&hist[dst[e] >> 8], 1);
    }
    __syncthreads();
    for (int i = tid; i < NBUCKET; i += 256)
        blockOff[(size_t)i * NBLKE + blockIdx.x] = hist[i];
}

// ======================= P2a: per-bucket scan over blocks =======================
__global__ __launch_bounds__(256) void p2a_kernel(int* __restrict__ blockOff,
                                                  int* __restrict__ bucketTotal) {
    __shared__ int wsum[4];
    int b = blockIdx.x, tid = threadIdx.x;
    size_t rowb = (size_t)b * NBLKE;
    int i0 = tid * 2, i1 = i0 + 1;
    int v0 = (i0 < NBLKE) ? blockOff[rowb + i0] : 0;
    int v1 = (i1 < NBLKE) ? blockOff[rowb + i1] : 0;
    int s = v0 + v1;
    int lane = tid & 63, wid = tid >> 6;
    int incl = s;
    #pragma unroll
    for (int o = 1; o < 64; o <<= 1) {
        int t = __shfl_up(incl, o, 64);
        if (lane >= o) incl += t;
    }
    if (lane == 63) wsum[wid] = incl;
    __syncthreads();
    int woff = 0;
    for (int w = 0; w < wid; ++w) woff += wsum[w];
    int excl = woff + incl - s;
    if (i0 < NBLKE) blockOff[rowb + i0] = excl;
    if (i1 < NBLKE) blockOff[rowb + i1] = excl + v0;
    if (tid == 255) bucketTotal[b] = woff + incl;
}

// ======================= P2b: scan bucket totals -> bucketStart =======================
__global__ __launch_bounds__(256) void p2b_kernel(const int* __restrict__ bucketTotal,
                                                  int* __restrict__ bucketStart,
                                                  int* __restrict__ rowptr) {
    __shared__ int wsum[4];
    int tid = threadIdx.x;
    int base = tid * 4;
    int v[4]; int s = 0;
    #pragma unroll
    for (int q = 0; q < 4; ++q) {
        int idx = base + q;
        v[q] = (idx < NBUCKET) ? bucketTotal[idx] : 0;
        s += v[q];
    }
    int lane = tid & 63, wid = tid >> 6;
    int incl = s;
    #pragma unroll
    for (int o = 1; o < 64; o <<= 1) {
        int t = __shfl_up(incl, o, 64);
        if (lane >= o) incl += t;
    }
    if (lane == 63) wsum[wid] = incl;
    __syncthreads();
    int woff = 0;
    for (int w = 0; w < wid; ++w) woff += wsum[w];
    int run = woff + incl - s;
    #pragma unroll
    for (int q = 0; q < 4; ++q) {
        int idx = base + q;
        if (idx < NBUCKET) bucketStart[idx] = run;
        run += v[q];
    }
    if (tid == 0) rowptr[N_NODES] = N_EDGES;
}

// ======================= P3: binned scatter of payload =======================
__global__ __launch_bounds__(256) void p3_binscatter(
    const int* __restrict__ dst, const int* __restrict__ src,
    const float* __restrict__ eattr,
    const int* __restrict__ blockOff, const int* __restrict__ bucketStart,
    unsigned int* __restrict__ metaArr, __half* __restrict__ wHarr) {
    __shared__ int cur[NBUCKET];
    int tid = threadIdx.x;
    for (int i = tid; i < NBUCKET; i += 256)
        cur[i] = bucketStart[i] + blockOff[(size_t)i * NBLKE + blockIdx.x];
    __syncthreads();
    size_t base = (size_t)blockIdx.x * CHUNK;
    for (int i = 0; i < CHUNK / 256; ++i) {
        size_t e = base + (size_t)i * 256 + tid;
        if (e < N_EDGES) {
            int d = dst[e];
            int b = d >> 8;
            int slot = atomicAdd(&cur[b], 1);
            unsigned int meta = ((unsigned int)(d & 255) << 18) | (unsigned int)src[e];
            float w = fminf(fmaxf(eattr[e], 0.f), 1.f);
            metaArr[slot] = meta;
            wHarr[slot] = __float2half(w);
        }
    }
}

// ======================= P4: per-bucket fine sort -> CSR + rowptr =======================
__global__ __launch_bounds__(256) void p4_buildcsr(
    const int* __restrict__ bucketStart, const int* __restrict__ bucketTotal,
    unsigned int* __restrict__ metaArr, __half* __restrict__ wHarr,
    int* __restrict__ rowptr) {
    __shared__ unsigned int stageM[STAGE_CAP];
    __shared__ __half stageW[STAGE_CAP];
    __shared__ int hist[NPB];
    __shared__ int wsum[4];
    int b = blockIdx.x, tid = threadIdx.x;
    int start = bucketStart[b];
    int count = bucketTotal[b];
    int nn = min(NPB, N_NODES - b * NPB);
    hist[tid] = 0;
    __syncthreads();
    for (int i = tid; i < count; i += 256) {
        unsigned int m = metaArr[start + i];
        stageM[i] = m;
        stageW[i] = wHarr[start + i];
        atomicAdd(&hist[m >> 18], 1);
    }
    __syncthreads();
    int v = hist[tid];
    int lane = tid & 63, wid = tid >> 6;
    int incl = v;
    #pragma unroll
    for (int o = 1; o < 64; o <<= 1) {
        int t = __shfl_up(incl, o, 64);
        if (lane >= o) incl += t;
    }
    if (lane == 63) wsum[wid] = incl;
    __syncthreads();
    int woff = 0;
    for (int w = 0; w < wid; ++w) woff += wsum[w];
    int excl = woff + incl - v;
    if (tid < nn) rowptr[b * NPB + tid] = start + excl;
    __syncthreads();
    hist[tid] = excl;
    __syncthreads();
    for (int i = tid; i < count; i += 256) {
        unsigned int m = stageM[i];
        int local = (int)(m >> 18);
        int pos = start + atomicAdd(&hist[local], 1);
        metaArr[pos] = m & 0x3FFFFu;
        wHarr[pos] = stageW[i];
    }
}

// ======================= agg1: gather-aggregate + ELU (16 lanes/node) =======================
__global__ __launch_bounds__(256) void agg1_kernel(
    const unsigned int* __restrict__ metaArr, const __half* __restrict__ wHarr,
    const int* __restrict__ rowptr, const __half2* __restrict__ hbufH,
    __half* __restrict__ rbufH, const float* __restrict__ bias1) {
    int t = blockIdx.x * 256 + threadIdx.x;
    int n = t >> 4;
    if (n >= N_NODES) return;
    int c = t & 15;
    int beg = rowptr[n], end = rowptr[n + 1];
    float acc = 0.f;
    for (int p = beg; p < end; ++p) {
        int s = (int)metaArr[p];
        float b1 = __half2float(wHarr[p]);
        float2 h = __half22float2(hbufH[(size_t)s * HID + c]);
        acc += fmaf(b1, h.y - h.x, h.x);
    }
    float invd = 1.0f / fmaxf((float)(end - beg), 1.0f);
    float r = __half2float(rbufH[(size_t)n * HID + c]);
    float vv = fmaf(acc, invd, r) + bias1[c];
    float hv = vv > 0.f ? vv : expm1f(vv);
    rbufH[(size_t)n * HID + c] = __float2half(hv);
}

// ======================= node1b: tiny layer-2 transforms =======================
__global__ __launch_bounds__(256) void node1b_kernel(
    const __half* __restrict__ rbufH, const float* __restrict__ W2,
    const float* __restrict__ root2,
    __half2* __restrict__ h2buf, float* __restrict__ r2buf) {
    int n = blockIdx.x * 256 + threadIdx.x;
    if (n >= N_NODES) return;
    float h[HID];
    #pragma unroll
    for (int k = 0; k < HID; ++k) h[k] = __half2float(rbufH[(size_t)n * HID + k]);
    float o0[NCLS], o1[NCLS], orr[NCLS];
    #pragma unroll
    for (int j = 0; j < NCLS; ++j) { o0[j] = 0.f; o1[j] = 0.f; orr[j] = 0.f; }
    const float* __restrict__ W2b = W2 + HID * NCLS;
    #pragma unroll
    for (int k = 0; k < HID; ++k) {
        #pragma unroll
        for (int j = 0; j < NCLS; ++j) {
            o0[j]  = fmaf(h[k], W2 [k * NCLS + j], o0[j]);
            o1[j]  = fmaf(h[k], W2b[k * NCLS + j], o1[j]);
            orr[j] = fmaf(h[k], root2[k * NCLS + j], orr[j]);
        }
    }
    __half2* hb = h2buf + (size_t)n * 8;
    float*   r2 = r2buf + (size_t)n * 8;
    #pragma unroll
    for (int j = 0; j < NCLS; ++j) {
        hb[j] = __floats2half2_rn(o0[j], o1[j]);
        r2[j] = orr[j];
    }
    hb[7] = __floats2half2_rn(0.f, 0.f);
    r2[7] = 0.f;
}

// ======================= agg2: gather-aggregate + log_softmax (8 lanes/node) ==========
__global__ __launch_bounds__(256) void agg2_kernel(
    const unsigned int* __restrict__ metaArr, const __half* __restrict__ wHarr,
    const int* __restrict__ rowptr, const __half2* __restrict__ h2buf,
    const float* __restrict__ r2buf, const float* __restrict__ bias2,
    float* __restrict__ out) {
    int t = blockIdx.x * 256 + threadIdx.x;
    int n = t >> 3;
    if (n >= N_NODES) return;
    int j = t & 7;
    int beg = rowptr[n], end = rowptr[n + 1];
    float acc = 0.f;
    for (int p = beg; p < end; ++p) {
        int s = (int)metaArr[p];
        float b1 = __half2float(wHarr[p]);
        float2 m = __half22float2(h2buf[(size_t)s * 8 + j]);
        acc += fmaf(b1, m.y - m.x, m.x);
    }
    float invd = 1.0f / fmaxf((float)(end - beg), 1.0f);
    float v = fmaf(acc, invd, r2buf[(size_t)n * 8 + j]) + ((j < NCLS) ? bias2[j] : 0.f);
    if (j == NCLS) v = -INFINITY;
    float mx = v;
    mx = fmaxf(mx, __shfl_xor(mx, 1, 8));
    mx = fmaxf(mx, __shfl_xor(mx, 2, 8));
    mx = fmaxf(mx, __shfl_xor(mx, 4, 8));
    float ex = expf(v - mx);
    float sm = ex;
    sm += __shfl_xor(sm, 1, 8);
    sm += __shfl_xor(sm, 2, 8);
    sm += __shfl_xor(sm, 4, 8);
    float lse = mx + logf(sm);
    if (j < NCLS) out[(size_t)n * NCLS + j] = v - lse;
}

extern "C" void kernel_launch(void* const* d_in, const int* in_sizes, int n_in,
                              void* d_out, int out_size, void* d_ws, size_t ws_size,
                              hipStream_t stream) {
    const float* x     = (const float*)d_in[0];
    const float* eattr = (const float*)d_in[1];
    const int*   src   = (const int*)d_in[2];
    const int*   dst   = (const int*)d_in[3];
    const float* W1    = (const float*)d_in[4];
    const float* root1 = (const float*)d_in[5];
    const float* bias1 = (const float*)d_in[6];
    const float* W2    = (const float*)d_in[7];
    const float* root2 = (const float*)d_in[8];
    const float* bias2 = (const float*)d_in[9];
    float* out = (float*)d_out;

    // ---------- workspace layout (~60 MB) ----------
    char* wp = (char*)d_ws;
    unsigned int* metaArr = (unsigned int*)wp;  wp += (size_t)N_EDGES * 4;           // 25.6 MB
    __half*       wHarr   = (__half*)wp;        wp += (size_t)N_EDGES * 2;           // 12.8 MB
    int* blockOff    = (int*)wp;                wp += (size_t)NBUCKET * NBLKE * 4;   // 1.22 MB
    int* bucketTotal = (int*)wp;                wp += 1024 * 4;
    int* bucketStart = (int*)wp;                wp += 1024 * 4;
    int* rowptr      = (int*)wp;                wp += (size_t)(N_NODES + 4) * 4;     // 0.8 MB
    __half* Bf       = (__half*)wp;             wp += (size_t)3 * 16 * 64 * 8 * 2;   // 48 KB
    __half2* hbufH   = (__half2*)wp;            wp += (size_t)N_NODES * HID * 4;     // 12.8 MB
    __half*  rbufH   = (__half*)wp;             wp += (size_t)N_NODES * HID * 2;     // 6.4 MB
    // aliases: hbufH region is dead after agg1
    __half2* h2buf = hbufH;                                          // N*8 half2
    float*   r2buf = (float*)(hbufH + (size_t)N_NODES * 8);          // N*8 f32

    const int node_blocks = (N_NODES + 255) / 256;  // 782

    hipLaunchKernelGGL(packB_kernel, dim3((3 * 16 * 64 + 255) / 256), dim3(256), 0, stream,
                       W1, root1, Bf);
    hipLaunchKernelGGL(gemm1_kernel, dim3(N_NODES / GROWS), dim3(256), 0, stream,
                       x, Bf, hbufH, rbufH);
    hipLaunchKernelGGL(p1_bincount, dim3(NBLKE), dim3(256), 0, stream, dst, blockOff);
    hipLaunchKernelGGL(p2a_kernel, dim3(NBUCKET), dim3(256), 0, stream,
                       blockOff, bucketTotal);
    hipLaunchKernelGGL(p2b_kernel, dim3(1), dim3(256), 0, stream,
                       bucketTotal, bucketStart, rowptr);
    hipLaunchKernelGGL(p3_binscatter, dim3(NBLKE), dim3(256), 0, stream,
                       dst, src, eattr, blockOff, bucketStart, metaArr, wHarr);
    hipLaunchKernelGGL(p4_buildcsr, dim3(NBUCKET), dim3(256), 0, stream,
                       bucketStart, bucketTotal, metaArr, wHarr, rowptr);
    hipLaunchKernelGGL(agg1_kernel, dim3((N_NODES * 16 + 255) / 256), dim3(256), 0, stream,
                       metaArr, wHarr, rowptr, hbufH, rbufH, bias1);
    hipLaunchKernelGGL(node1b_kernel, dim3(node_blocks), dim3(256), 0, stream,
                       rbufH, W2, root2, h2buf, r2buf);
    hipLaunchKernelGGL(agg2_kernel, dim3((N_NODES * 8 + 255) / 256), dim3(256), 0, stream,
                       metaArr, wHarr, rowptr, h2buf, r2buf, bias2, out);
}

// Round 10
// 745.653 us; speedup vs baseline: 1.7774x; 1.0616x over previous
//
#include <hip/hip_runtime.h>
#include <hip/hip_fp16.h>
#include <math.h>

#define N_NODES 200000
#define N_EDGES 6400000
#define F_INF   512
#define HID     16
#define NCLS    7

#define NPB      1024                              // nodes per bucket
#define NBUCKET  ((N_NODES + NPB - 1) / NPB)       // 196
#define CHUNK    16384
#define NBLKE    ((N_EDGES + CHUNK - 1) / CHUNK)   // 391
#define P4CAP    35328                             // mean 32768 + ~14 sigma

// ---- gemm1 (MFMA) geometry ----
#define GROWS 64     // rows per block (4 waves x 16)
#define KCHG  256    // K-chunk in fp32 elems (2 chunks of 256 = 512)
#define ASTR  264    // LDS row stride in halves (528B = 4 banks mod 32 -> uniform)

typedef _Float16 f16x8 __attribute__((ext_vector_type(8)));
typedef float    f32x4 __attribute__((ext_vector_type(4)));

// ======================= pack (W1[0]|W1[1]|root1) into MFMA B-fragment order ========
__global__ __launch_bounds__(256) void packB_kernel(
    const float* __restrict__ W1, const float* __restrict__ root1,
    __half* __restrict__ Bf) {
    int tt = blockIdx.x * 256 + threadIdx.x;    // 3*16*64 = 3072
    if (tt >= 3 * 16 * 64) return;
    int lane = tt & 63, kk = (tt >> 6) & 15, t = tt >> 10;
    int col = lane & 15;
    int kbase = kk * 32 + (lane >> 4) * 8;
    const float* __restrict__ srcm = (t == 0) ? W1
                                   : (t == 1) ? (W1 + F_INF * HID) : root1;
    #pragma unroll
    for (int j = 0; j < 8; ++j)
        Bf[(size_t)tt * 8 + j] = __float2half(srcm[(kbase + j) * HID + col]);
}

// ======================= layer 1 GEMM via MFMA =======================
__global__ __launch_bounds__(256) void gemm1_kernel(
    const float* __restrict__ x, const __half* __restrict__ Bf,
    __half2* __restrict__ hbufH, __half* __restrict__ rbufH) {
    __shared__ __half As[GROWS * ASTR];          // 33792 B
    int tid = threadIdx.x;
    int l = tid & 63, w = tid >> 6;
    int rowBase = blockIdx.x * GROWS;

    f32x4 acc0 = {0.f, 0.f, 0.f, 0.f};
    f32x4 acc1 = {0.f, 0.f, 0.f, 0.f};
    f32x4 acc2 = {0.f, 0.f, 0.f, 0.f};

    const __half* __restrict__ Arow = &As[(w * 16 + (l & 15)) * ASTR + (l >> 4) * 8];

    for (int ch = 0; ch < F_INF / KCHG; ++ch) {  // 2 chunks
        __syncthreads();
        #pragma unroll
        for (int j = 0; j < 16; ++j) {
            int row = w * 16 + j;
            float4 v = *(const float4*)(x + (size_t)(rowBase + row) * F_INF
                                          + ch * KCHG + l * 4);
            union { __half2 h2[2]; float2 f2; } u;
            u.h2[0] = __floats2half2_rn(v.x, v.y);
            u.h2[1] = __floats2half2_rn(v.z, v.w);
            *(float2*)(&As[row * ASTR + l * 4]) = u.f2;
        }
        __syncthreads();
        #pragma unroll
        for (int kkl = 0; kkl < 8; ++kkl) {
            f16x8 a = *(const f16x8*)(Arow + kkl * 32);
            int kkg = ch * 8 + kkl;
            const __half* bp = Bf + ((size_t)kkg * 64 + l) * 8;
            f16x8 b0 = *(const f16x8*)(bp);
            f16x8 b1 = *(const f16x8*)(bp + 16 * 64 * 8);
            f16x8 b2 = *(const f16x8*)(bp + 2 * 16 * 64 * 8);
            acc0 = __builtin_amdgcn_mfma_f32_16x16x32_f16(a, b0, acc0, 0, 0, 0);
            acc1 = __builtin_amdgcn_mfma_f32_16x16x32_f16(a, b1, acc1, 0, 0, 0);
            acc2 = __builtin_amdgcn_mfma_f32_16x16x32_f16(a, b2, acc2, 0, 0, 0);
        }
    }
    int c = l & 15;
    int rbase = rowBase + w * 16 + (l >> 4) * 4;
    #pragma unroll
    for (int r = 0; r < 4; ++r) {
        int n = rbase + r;
        hbufH[(size_t)n * HID + c] = __floats2half2_rn(acc0[r], acc1[r]);
        rbufH[(size_t)n * HID + c] = __float2half(acc2[r]);
    }
}

// ======================= P1: per-block bucket histogram =======================
__global__ __launch_bounds__(256) void p1_bincount(const int* __restrict__ dst,
                                                   int* __restrict__ blockOff) {
    __shared__ int hist[NBUCKET];
    int tid = threadIdx.x;
    for (int i = tid; i < NBUCKET; i += 256) hist[i] = 0;
    __syncthreads();
    size_t base = (size_t)blockIdx.x * CHUNK;
    for (int i = 0; i < CHUNK / 256; ++i) {
        size_t e = base + (size_t)i * 256 + tid;
        if (e < N_EDGES) atomicAdd(&hist[dst[e] >> 10], 1);
    }
    __syncthreads();
    for (int i = tid; i < NBUCKET; i += 256)
        blockOff[(size_t)i * NBLKE + blockIdx.x] = hist[i];
}

// ======================= P2a: per-bucket scan over blocks =======================
__global__ __launch_bounds__(256) void p2a_kernel(int* __restrict__ blockOff,
                                                  int* __restrict__ bucketTotal) {
    __shared__ int wsum[4];
    int b = blockIdx.x, tid = threadIdx.x;
    size_t rowb = (size_t)b * NBLKE;
    int i0 = tid * 2, i1 = i0 + 1;
    int v0 = (i0 < NBLKE) ? blockOff[rowb + i0] : 0;
    int v1 = (i1 < NBLKE) ? blockOff[rowb + i1] : 0;
    int s = v0 + v1;
    int lane = tid & 63, wid = tid >> 6;
    int incl = s;
    #pragma unroll
    for (int o = 1; o < 64; o <<= 1) {
        int t = __shfl_up(incl, o, 64);
        if (lane >= o) incl += t;
    }
    if (lane == 63) wsum[wid] = incl;
    __syncthreads();
    int woff = 0;
    for (int w = 0; w < wid; ++w) woff += wsum[w];
    int excl = woff + incl - s;
    if (i0 < NBLKE) blockOff[rowb + i0] = excl;
    if (i1 < NBLKE) blockOff[rowb + i1] = excl + v0;
    if (tid == 255) bucketTotal[b] = woff + incl;
}

// ======================= P2b: scan bucket totals -> bucketStart =======================
__global__ __launch_bounds__(256) void p2b_kernel(const int* __restrict__ bucketTotal,
                                                  int* __restrict__ bucketStart,
                                                  int* __restrict__ rowptr) {
    __shared__ int wsum[4];
    int tid = threadIdx.x;
    int base = tid * 4;
    int v[4]; int s = 0;
    #pragma unroll
    for (int q = 0; q < 4; ++q) {
        int idx = base + q;
        v[q] = (idx < NBUCKET) ? bucketTotal[idx] : 0;
        s += v[q];
    }
    int lane = tid & 63, wid = tid >> 6;
    int incl = s;
    #pragma unroll
    for (int o = 1; o < 64; o <<= 1) {
        int t = __shfl_up(incl, o, 64);
        if (lane >= o) incl += t;
    }
    if (lane == 63) wsum[wid] = incl;
    __syncthreads();
    int woff = 0;
    for (int w = 0; w < wid; ++w) woff += wsum[w];
    int run = woff + incl - s;
    #pragma unroll
    for (int q = 0; q < 4; ++q) {
        int idx = base + q;
        if (idx < NBUCKET) bucketStart[idx] = run;
        run += v[q];
    }
    if (tid == 0) rowptr[N_NODES] = N_EDGES;
}

// ======================= P3: binned scatter of payload (196 buckets) =================
// meta = (local[10b] << 18) | src[18b]
__global__ __launch_bounds__(256) void p3_binscatter(
    const int* __restrict__ dst, const int* __restrict__ src,
    const float* __restrict__ eattr,
    const int* __restrict__ blockOff, const int* __restrict__ bucketStart,
    unsigned int* __restrict__ metaArr, __half* __restrict__ wHarr) {
    __shared__ int cur[NBUCKET];
    int tid = threadIdx.x;
    for (int i = tid; i < NBUCKET; i += 256)
        cur[i] = bucketStart[i] + blockOff[(size_t)i * NBLKE + blockIdx.x];
    __syncthreads();
    size_t base = (size_t)blockIdx.x * CHUNK;
    for (int i = 0; i < CHUNK / 256; ++i) {
        size_t e = base + (size_t)i * 256 + tid;
        if (e < N_EDGES) {
            int d = dst[e];
            int b = d >> 10;
            int slot = atomicAdd(&cur[b], 1);
            unsigned int meta = ((unsigned int)(d & 1023) << 18) | (unsigned int)src[e];
            float w = fminf(fmaxf(eattr[e], 0.f), 1.f);
            metaArr[slot] = meta;
            wHarr[slot] = __float2half(w);
        }
    }
}

// ======================= P4: per-bucket fine sort (1024 nodes) -> CSR + rowptr ========
__global__ __launch_bounds__(256) void p4_buildcsr(
    const int* __restrict__ bucketStart, const int* __restrict__ bucketTotal,
    unsigned int* __restrict__ metaArr, const __half* __restrict__ wHarr,
    __half* __restrict__ wHarr2, int* __restrict__ rowptr) {
    __shared__ unsigned int stageM[P4CAP];       // 141.3 KB
    __shared__ int hist[NPB];                    // 4 KB
    __shared__ int wsum[4];
    int b = blockIdx.x, tid = threadIdx.x;
    int start = bucketStart[b];
    int count = bucketTotal[b];
    if (count > P4CAP) count = P4CAP;            // probability ~0
    int nn = min(NPB, N_NODES - b * NPB);
    for (int i = tid; i < NPB; i += 256) hist[i] = 0;
    __syncthreads();
    for (int i = tid; i < count; i += 256) {
        unsigned int m = metaArr[start + i];
        stageM[i] = m;
        atomicAdd(&hist[m >> 18], 1);
    }
    __syncthreads();
    // exclusive scan of hist[1024]: each thread owns 4 consecutive entries
    int base = tid * 4;
    int v0 = hist[base], v1 = hist[base + 1], v2 = hist[base + 2], v3 = hist[base + 3];
    int s = v0 + v1 + v2 + v3;
    int lane = tid & 63, wid = tid >> 6;
    int incl = s;
    #pragma unroll
    for (int o = 1; o < 64; o <<= 1) {
        int t = __shfl_up(incl, o, 64);
        if (lane >= o) incl += t;
    }
    if (lane == 63) wsum[wid] = incl;
    __syncthreads();
    int woff = 0;
    for (int w = 0; w < wid; ++w) woff += wsum[w];
    int excl = woff + incl - s;
    int c0 = excl, c1 = excl + v0, c2 = excl + v0 + v1, c3 = excl + v0 + v1 + v2;
    hist[base] = c0; hist[base + 1] = c1; hist[base + 2] = c2; hist[base + 3] = c3;
    if (base + 0 < nn) rowptr[b * NPB + base + 0] = start + c0;
    if (base + 1 < nn) rowptr[b * NPB + base + 1] = start + c1;
    if (base + 2 < nn) rowptr[b * NPB + base + 2] = start + c2;
    if (base + 3 < nn) rowptr[b * NPB + base + 3] = start + c3;
    __syncthreads();
    // placement: metaArr in place (src only), wHarr permuted into wHarr2
    for (int i = tid; i < count; i += 256) {
        unsigned int m = stageM[i];
        int local = (int)(m >> 18);
        int pos = start + atomicAdd(&hist[local], 1);
        metaArr[pos] = m & 0x3FFFFu;
        wHarr2[pos] = wHarr[start + i];
    }
}

// ======================= agg1: gather-aggregate + ELU (16 lanes/node) =================
__global__ __launch_bounds__(256) void agg1_kernel(
    const unsigned int* __restrict__ metaArr, const __half* __restrict__ wHarr,
    const int* __restrict__ rowptr, const __half2* __restrict__ hbufH,
    __half* __restrict__ rbufH, const float* __restrict__ bias1) {
    int t = blockIdx.x * 256 + threadIdx.x;
    int n = t >> 4;
    if (n >= N_NODES) return;
    int c = t & 15;
    int beg = rowptr[n], end = rowptr[n + 1];
    float acc = 0.f;
    for (int p = beg; p < end; ++p) {
        int s = (int)metaArr[p];
        float b1 = __half2float(wHarr[p]);
        float2 h = __half22float2(hbufH[(size_t)s * HID + c]);
        acc += fmaf(b1, h.y - h.x, h.x);
    }
    float invd = 1.0f / fmaxf((float)(end - beg), 1.0f);
    float r = __half2float(rbufH[(size_t)n * HID + c]);
    float vv = fmaf(acc, invd, r) + bias1[c];
    float hv = vv > 0.f ? vv : expm1f(vv);
    rbufH[(size_t)n * HID + c] = __float2half(hv);
}

// ======================= node1b: tiny layer-2 transforms =======================
__global__ __launch_bounds__(256) void node1b_kernel(
    const __half* __restrict__ rbufH, const float* __restrict__ W2,
    const float* __restrict__ root2,
    __half2* __restrict__ h2buf, float* __restrict__ r2buf) {
    int n = blockIdx.x * 256 + threadIdx.x;
    if (n >= N_NODES) return;
    float h[HID];
    #pragma unroll
    for (int k = 0; k < HID; ++k) h[k] = __half2float(rbufH[(size_t)n * HID + k]);
    float o0[NCLS], o1[NCLS], orr[NCLS];
    #pragma unroll
    for (int j = 0; j < NCLS; ++j) { o0[j] = 0.f; o1[j] = 0.f; orr[j] = 0.f; }
    const float* __restrict__ W2b = W2 + HID * NCLS;
    #pragma unroll
    for (int k = 0; k < HID; ++k) {
        #pragma unroll
        for (int j = 0; j < NCLS; ++j) {
            o0[j]  = fmaf(h[k], W2 [k * NCLS + j], o0[j]);
            o1[j]  = fmaf(h[k], W2b[k * NCLS + j], o1[j]);
            orr[j] = fmaf(h[k], root2[k * NCLS + j], orr[j]);
        }
    }
    __half2* hb = h2buf + (size_t)n * 8;
    float*   r2 = r2buf + (size_t)n * 8;
    #pragma unroll
    for (int j = 0; j < NCLS; ++j) {
        hb[j] = __floats2half2_rn(o0[j], o1[j]);
        r2[j] = orr[j];
    }
    hb[7] = __floats2half2_rn(0.f, 0.f);
    r2[7] = 0.f;
}

// ======================= agg2: gather-aggregate + log_softmax (8 lanes/node) ==========
__global__ __launch_bounds__(256) void agg2_kernel(
    const unsigned int* __restrict__ metaArr, const __half* __restrict__ wHarr,
    const int* __restrict__ rowptr, const __half2* __restrict__ h2buf,
    const float* __restrict__ r2buf, const float* __restrict__ bias2,
    float* __restrict__ out) {
    int t = blockIdx.x * 256 + threadIdx.x;
    int n = t >> 3;
    if (n >= N_NODES) return;
    int j = t & 7;
    int beg = rowptr[n], end = rowptr[n + 1];
    float acc = 0.f;
    for (int p = beg; p < end; ++p) {
        int s = (int)metaArr[p];
        float b1 = __half2float(wHarr[p]);
        float2 m = __half22float2(h2buf[(size_t)s * 8 + j]);
        acc += fmaf(b1, m.y - m.x, m.x);
    }
    float invd = 1.0f / fmaxf((float)(end - beg), 1.0f);
    float v = fmaf(acc, invd, r2buf[(size_t)n * 8 + j]) + ((j < NCLS) ? bias2[j] : 0.f);
    if (j == NCLS) v = -INFINITY;
    float mx = v;
    mx = fmaxf(mx, __shfl_xor(mx, 1, 8));
    mx = fmaxf(mx, __shfl_xor(mx, 2, 8));
    mx = fmaxf(mx, __shfl_xor(mx, 4, 8));
    float ex = expf(v - mx);
    float sm = ex;
    sm += __shfl_xor(sm, 1, 8);
    sm += __shfl_xor(sm, 2, 8);
    sm += __shfl_xor(sm, 4, 8);
    float lse = mx + logf(sm);
    if (j < NCLS) out[(size_t)n * NCLS + j] = v - lse;
}

extern "C" void kernel_launch(void* const* d_in, const int* in_sizes, int n_in,
                              void* d_out, int out_size, void* d_ws, size_t ws_size,
                              hipStream_t stream) {
    const float* x     = (const float*)d_in[0];
    const float* eattr = (const float*)d_in[1];
    const int*   src   = (const int*)d_in[2];
    const int*   dst   = (const int*)d_in[3];
    const float* W1    = (const float*)d_in[4];
    const float* root1 = (const float*)d_in[5];
    const float* bias1 = (const float*)d_in[6];
    const float* W2    = (const float*)d_in[7];
    const float* root2 = (const float*)d_in[8];
    const float* bias2 = (const float*)d_in[9];
    float* out = (float*)d_out;

    // ---------- workspace layout (~72 MB) ----------
    char* wp = (char*)d_ws;
    unsigned int* metaArr = (unsigned int*)wp;  wp += (size_t)N_EDGES * 4;           // 25.6 MB
    __half*       wHarr   = (__half*)wp;        wp += (size_t)N_EDGES * 2;           // 12.8 MB
    __half*       wHarr2  = (__half*)wp;        wp += (size_t)N_EDGES * 2;           // 12.8 MB
    int* blockOff    = (int*)wp;                wp += (size_t)NBUCKET * NBLKE * 4;   // 306 KB
    int* bucketTotal = (int*)wp;                wp += 1024 * 4;
    int* bucketStart = (int*)wp;                wp += 1024 * 4;
    int* rowptr      = (int*)wp;                wp += (size_t)(N_NODES + 4) * 4;     // 0.8 MB
    __half* Bf       = (__half*)wp;             wp += (size_t)3 * 16 * 64 * 8 * 2;   // 48 KB
    __half2* hbufH   = (__half2*)wp;            wp += (size_t)N_NODES * HID * 4;     // 12.8 MB
    __half*  rbufH   = (__half*)wp;             wp += (size_t)N_NODES * HID * 2;     // 6.4 MB
    // aliases: hbufH region is dead after agg1
    __half2* h2buf = hbufH;                                          // N*8 half2
    float*   r2buf = (float*)(hbufH + (size_t)N_NODES * 8);          // N*8 f32

    const int node_blocks = (N_NODES + 255) / 256;  // 782

    hipLaunchKernelGGL(packB_kernel, dim3((3 * 16 * 64 + 255) / 256), dim3(256), 0, stream,
                       W1, root1, Bf);
    hipLaunchKernelGGL(gemm1_kernel, dim3(N_NODES / GROWS), dim3(256), 0, stream,
                       x, Bf, hbufH, rbufH);
    hipLaunchKernelGGL(p1_bincount, dim3(NBLKE), dim3(256), 0, stream, dst, blockOff);
    hipLaunchKernelGGL(p2a_kernel, dim3(NBUCKET), dim3(256), 0, stream,
                       blockOff, bucketTotal);
    hipLaunchKernelGGL(p2b_kernel, dim3(1), dim3(256), 0, stream,
                       bucketTotal, bucketStart, rowptr);
    hipLaunchKernelGGL(p3_binscatter, dim3(NBLKE), dim3(256), 0, stream,
                       dst, src, eattr, blockOff, bucketStart, metaArr, wHarr);
    hipLaunchKernelGGL(p4_buildcsr, dim3(NBUCKET), dim3(256), 0, stream,
                       bucketStart, bucketTotal, metaArr, wHarr, wHarr2, rowptr);
    hipLaunchKernelGGL(agg1_kernel, dim3((N_NODES * 16 + 255) / 256), dim3(256), 0, stream,
                       metaArr, wHarr2, rowptr, hbufH, rbufH, bias1);
    hipLaunchKernelGGL(node1b_kernel, dim3(node_blocks), dim3(256), 0, stream,
                       rbufH, W2, root2, h2buf, r2buf);
    hipLaunchKernelGGL(agg2_kernel, dim3((N_NODES * 8 + 255) / 256), dim3(256), 0, stream,
                       metaArr, wHarr2, rowptr, h2buf, r2buf, bias2, out);
}